// Round 6
// baseline (857.027 us; speedup 1.0000x reference)
//
#include <hip/hip_runtime.h>
#include <cstdint>
#include <cstddef>

// ---------- problem constants ----------
#define DIM      1024
#define GROUP    16
#define LORA     20
#define NLAYERS  18
#define NBLOCKS  6
#define BATCH    8192
#define EPS      1e-5f

typedef __bf16 bf16_8 __attribute__((ext_vector_type(8)));
typedef __bf16 bf16_4 __attribute__((ext_vector_type(4)));
typedef float  f32x4  __attribute__((ext_vector_type(4)));

// ---------------------------------------------------------------------------
// Weight prep: W_total[l][o][k] = qw*scale + sum_r B[o][r]*A[r][k], split bf16
// hi/lo. Block = (layer, 32-row group, 512-col half) -> 1152 blocks.
// 4-deep explicit prefetch of qw/scale: 8 outstanding global loads per thread
// (R5 was 1-deep -> HBM-latency-bound at 29% BW).
// ---------------------------------------------------------------------------
__global__ __launch_bounds__(256) void wprep_kernel(
    const int* __restrict__ qw, const float* __restrict__ sc,
    const float* __restrict__ la, const float* __restrict__ lb,
    __bf16* __restrict__ whi, __bf16* __restrict__ wlo) {
  const int l  = blockIdx.x >> 6;          // 18 layers
  const int og = (blockIdx.x >> 1) & 31;   // 32 row-groups of 32
  const int cg = blockIdx.x & 1;           // 2 col-halves of 512
  const int tid = threadIdx.x;

  __shared__ float As[LORA * 512];   // 40 KB
  __shared__ float Bs[32 * LORA];    // 2.5 KB

  const float* Abase = la + (size_t)l * LORA * DIM + cg * 512;
#pragma unroll
  for (int i = 0; i < 10; ++i) {
    const int f4 = i * 256 + tid;
    const int j  = f4 >> 7;
    const int c4 = f4 & 127;
    ((float4*)As)[f4] = *(const float4*)(Abase + (size_t)j * DIM + c4 * 4);
  }
  const float* Bbase = lb + ((size_t)l * DIM + og * 32) * LORA;  // 640 floats
#pragma unroll
  for (int i = 0; i < 3; ++i) {
    const int idx = i * 256 + tid;
    if (idx < 32 * LORA) Bs[idx] = Bbase[idx];
  }
  __syncthreads();

  const int colg = (tid & 127) * 4;        // col within the 512 slice
  const int rh   = tid >> 7;               // row half (0/1): 16 rows each
#pragma unroll 1
  for (int sg = 0; sg < 4; ++sg) {
    int4  q[4];
    float sv[4];
    size_t wb[4];
#pragma unroll
    for (int u = 0; u < 4; ++u) {
      const int r    = rh * 16 + sg * 4 + u;
      const int orow = og * 32 + r;
      wb[u] = ((size_t)l * DIM + orow) * DIM + cg * 512 + colg;
      q[u]  = *(const int4*)&qw[wb[u]];
      sv[u] = sc[((size_t)l * DIM + orow) * (DIM / GROUP) + ((cg * 512 + colg) >> 4)];
    }
#pragma unroll
    for (int u = 0; u < 4; ++u) {
      const int r = rh * 16 + sg * 4 + u;
      float a0 = q[u].x * sv[u], a1 = q[u].y * sv[u],
            a2 = q[u].z * sv[u], a3 = q[u].w * sv[u];
      const float* Br = &Bs[r * LORA];
#pragma unroll
      for (int j = 0; j < LORA; ++j) {
        const float bj = Br[j];
        const float* Aj = &As[j * 512 + colg];
        a0 += bj * Aj[0]; a1 += bj * Aj[1]; a2 += bj * Aj[2]; a3 += bj * Aj[3];
      }
      const __bf16 h0 = (__bf16)a0, h1 = (__bf16)a1, h2 = (__bf16)a2, h3 = (__bf16)a3;
      const bf16_4 hv = {h0, h1, h2, h3};
      const bf16_4 lv = {(__bf16)(a0 - (float)h0), (__bf16)(a1 - (float)h1),
                         (__bf16)(a2 - (float)h2), (__bf16)(a3 - (float)h3)};
      *(bf16_4*)&whi[wb[u]] = hv;
      *(bf16_4*)&wlo[wb[u]] = lv;
    }
  }
}

// ---------------------------------------------------------------------------
// x prep: f32 -> single bf16
// ---------------------------------------------------------------------------
__global__ __launch_bounds__(256) void xprep_kernel(
    const float* __restrict__ x, __bf16* __restrict__ hi) {
  const size_t i = (size_t)blockIdx.x * 256 + threadIdx.x;
  const float4 v = ((const float4*)x)[i];
  const bf16_4 hv = {(__bf16)v.x, (__bf16)v.y, (__bf16)v.z, (__bf16)v.w};
  ((bf16_4*)hi)[i] = hv;
}

// ---------------------------------------------------------------------------
// 2-pass split-W bf16 GEMM (x single bf16; W = Wh + Wl).
// Tile 128x128, BK=32, 256 thr (4 waves 2x2), static 48KB LDS, 2-buf.
// Block map: tn = bid&7 -> all blocks of feature-panel tn land on XCD tn
// (round-robin dispatch): W panel (512KB) stays L2-resident per XCD; X panels
// stream from L3 once per XCD. tm = bid>>3 streams X sequentially.
// ---------------------------------------------------------------------------
#define GBUF    12288   // elems per buffer (24 KB)
#define GOFF_WH 4096
#define GOFF_WL 8192

__device__ __forceinline__ void stageR(const __bf16* __restrict__ g, int row0, int k0,
                                       __bf16* lds, int tid) {
  const int wvbase = (tid >> 6) * 512;     // elems: wave-uniform LDS base
#pragma unroll
  for (int i = 0; i < 2; ++i) {
    const int D = i * 4096 + tid * 16;     // byte in 8KB region
    const int r  = D >> 6;                 // 64 B per row (BK=32 bf16)
    const int ce = (D & 63) >> 1;
    const __bf16* gp = g + (size_t)(row0 + r) * DIM + k0 + ce;
    __builtin_amdgcn_global_load_lds(
        (const __attribute__((address_space(1))) void*)gp,
        (__attribute__((address_space(3))) void*)(lds + i * 2048 + wvbase), 16, 0, 0);
  }
}

template <bool RELU_OUT>
__global__ __launch_bounds__(256, 3) void gemm2_kernel(
    const __bf16* __restrict__ X, const __bf16* __restrict__ Wh,
    const __bf16* __restrict__ Wl, const float* __restrict__ bias,
    __bf16* __restrict__ Oh,
    const float* __restrict__ Hin, float* __restrict__ Sout) {
  __shared__ __bf16 smem[2 * GBUF];        // 48 KB

  const int tid  = threadIdx.x;
  const int lane = tid & 63;
  const int wv   = tid >> 6;
  const int wm   = wv >> 1;                // feature half (2 x 64)
  const int wn   = wv & 1;                 // batch half   (2 x 64)
  // XCD-resident W: tn == XCD id (bid % 8 round-robin), tm streams X
  const int tn = blockIdx.x & 7;
  const int tm = blockIdx.x >> 3;
  const int rowX = tm * 128, rowW = tn * 128;

  const int lr   = lane & 15;
  const int slot = lane >> 4;

  int offX[4], offW[4];
#pragma unroll
  for (int n = 0; n < 4; ++n) offX[n] = (wn * 64 + n * 16 + lr) * 32 + slot * 8;
#pragma unroll
  for (int m = 0; m < 4; ++m) offW[m] = GOFF_WH + (wm * 64 + m * 16 + lr) * 32 + slot * 8;

  f32x4 acc[4][4];
#pragma unroll
  for (int m = 0; m < 4; ++m)
#pragma unroll
    for (int n = 0; n < 4; ++n) acc[m][n] = f32x4{0.f, 0.f, 0.f, 0.f};

  auto stage_tile = [&](int k0, __bf16* sb) {
    stageR(X,  rowX, k0, sb, tid);
    stageR(Wh, rowW, k0, sb + GOFF_WH, tid);
    stageR(Wl, rowW, k0, sb + GOFF_WL, tid);
  };

  auto compute_tile = [&](const __bf16* buf) {
    bf16_8 xf[4];
#pragma unroll
    for (int n = 0; n < 4; ++n) xf[n] = *(const bf16_8*)&buf[offX[n]];
#pragma unroll
    for (int m = 0; m < 4; ++m) {
      const bf16_8 w_h = *(const bf16_8*)&buf[offW[m]];
      const bf16_8 w_l = *(const bf16_8*)&buf[offW[m] + (GOFF_WL - GOFF_WH)];
#pragma unroll
      for (int n = 0; n < 4; ++n) {
        acc[m][n] = __builtin_amdgcn_mfma_f32_16x16x32_bf16(w_h, xf[n], acc[m][n], 0, 0, 0);
        acc[m][n] = __builtin_amdgcn_mfma_f32_16x16x32_bf16(w_l, xf[n], acc[m][n], 0, 0, 0);
      }
    }
  };

  stage_tile(0, smem);
  __syncthreads();

  int cur = 0;
#pragma unroll 1
  for (int kt = 0; kt < 31; ++kt) {
    stage_tile((kt + 1) * 32, smem + (cur ^ 1) * GBUF);
    compute_tile(smem + cur * GBUF);
    __syncthreads();      // drains vmcnt(0): next buffer ready; cur reusable
    cur ^= 1;
  }
  compute_tile(smem + cur * GBUF);

  // epilogue: D reg-quad = 4 consecutive features of one batch row
  const int g4 = slot * 4;
#pragma unroll
  for (int m = 0; m < 4; ++m) {
    const int feat = tn * 128 + wm * 64 + m * 16 + g4;
    const float4 bv = *(const float4*)&bias[feat];
#pragma unroll
    for (int n = 0; n < 4; ++n) {
      const int nb = tm * 128 + wn * 64 + n * 16 + lr;
      const size_t base = (size_t)nb * DIM + feat;
      float v0 = acc[m][n][0] + bv.x;
      float v1 = acc[m][n][1] + bv.y;
      float v2 = acc[m][n][2] + bv.z;
      float v3 = acc[m][n][3] + bv.w;
      if constexpr (RELU_OUT) {
        const bf16_4 hv = {(__bf16)fmaxf(v0, 0.f), (__bf16)fmaxf(v1, 0.f),
                           (__bf16)fmaxf(v2, 0.f), (__bf16)fmaxf(v3, 0.f)};
        *(bf16_4*)&Oh[base] = hv;
      } else {
        const float4 h = *(const float4*)&Hin[base];
        *(float4*)&Sout[base] = float4{v0 + h.x, v1 + h.y, v2 + h.z, v3 + h.w};
      }
    }
  }
}

// ---------------------------------------------------------------------------
// Row LayerNorm: H = LN(S)*w+b (f32) plus bf16 cast (next block's GEMM input).
// ---------------------------------------------------------------------------
__global__ __launch_bounds__(256) void ln_kernel(
    const float* __restrict__ S, const float* __restrict__ w,
    const float* __restrict__ b, float* __restrict__ H,
    __bf16* __restrict__ phi) {
  const int row = blockIdx.x;
  const int tid = threadIdx.x;
  const int lane = tid & 63;
  const int wv = tid >> 6;
  const float4 v = ((const float4*)(S + (size_t)row * DIM))[tid];

  float s = v.x + v.y + v.z + v.w;
#pragma unroll
  for (int m = 32; m; m >>= 1) s += __shfl_xor(s, m, 64);
  __shared__ float red[8];
  if (lane == 0) red[wv] = s;
  __syncthreads();
  const float mean = (red[0] + red[1] + red[2] + red[3]) * (1.f / DIM);

  const float d0 = v.x - mean, d1 = v.y - mean, d2 = v.z - mean, d3 = v.w - mean;
  float q = d0 * d0 + d1 * d1 + d2 * d2 + d3 * d3;
#pragma unroll
  for (int m = 32; m; m >>= 1) q += __shfl_xor(q, m, 64);
  if (lane == 0) red[4 + wv] = q;
  __syncthreads();
  const float var = (red[4] + red[5] + red[6] + red[7]) * (1.f / DIM);
  const float inv = 1.f / sqrtf(var + EPS);

  const float4 wv4 = ((const float4*)w)[tid];
  const float4 bv4 = ((const float4*)b)[tid];
  const float y0 = d0 * inv * wv4.x + bv4.x;
  const float y1 = d1 * inv * wv4.y + bv4.y;
  const float y2 = d2 * inv * wv4.z + bv4.z;
  const float y3 = d3 * inv * wv4.w + bv4.w;

  ((float4*)(H + (size_t)row * DIM))[tid] = float4{y0, y1, y2, y3};
  const bf16_4 hv = {(__bf16)y0, (__bf16)y1, (__bf16)y2, (__bf16)y3};
  ((bf16_4*)phi)[(size_t)row * (DIM / 4) + tid] = hv;
}

// ---------------------------------------------------------------------------
// launch
// ---------------------------------------------------------------------------
extern "C" void kernel_launch(void* const* d_in, const int* in_sizes, int n_in,
                              void* d_out, int out_size, void* d_ws, size_t ws_size,
                              hipStream_t stream) {
  const float* x   = (const float*)d_in[0];
  const int*   qw  = (const int*)d_in[1];
  const float* sc  = (const float*)d_in[2];
  const float* bias= (const float*)d_in[3];
  const float* la  = (const float*)d_in[4];
  const float* lb  = (const float*)d_in[5];
  const float* lnw = (const float*)d_in[6];
  const float* lnb = (const float*)d_in[7];
  float* out = (float*)d_out;
  char* ws = (char*)d_ws;

  // workspace layout (bytes): WHI 36M | WLO 36M | X0 16M | X1 16M | Sb 32M | Hb 32M
  __bf16* WHI = (__bf16*)(ws);
  __bf16* WLO = (__bf16*)(ws + 37748736);
  __bf16* X0  = (__bf16*)(ws + 75497472);
  __bf16* X1  = (__bf16*)(ws + 92274688);
  float*  Sb  = (float*)(ws + 109051904);
  float*  Hb  = (float*)(ws + 142606336);
  (void)ws_size; (void)in_sizes; (void)n_in; (void)out_size;

  xprep_kernel<<<BATCH * DIM / (256 * 4), 256, 0, stream>>>(x, X0);
  wprep_kernel<<<NLAYERS * 64, 256, 0, stream>>>(qw, sc, la, lb, WHI, WLO);

  const dim3 ggrid(BATCH / 128 * (DIM / 128));  // 64 * 8 = 512
  for (int blk = 0; blk < NBLOCKS; ++blk) {
    const int li = blk * 3;
    const size_t w0 = (size_t)li * DIM * DIM;
    const size_t w1 = (size_t)(li + 1) * DIM * DIM;
    const size_t w2 = (size_t)(li + 2) * DIM * DIM;

    gemm2_kernel<true><<<ggrid, 256, 0, stream>>>(
        X0, WHI + w0, WLO + w0, bias + (size_t)li * DIM, X1, nullptr, nullptr);
    gemm2_kernel<true><<<ggrid, 256, 0, stream>>>(
        X1, WHI + w1, WLO + w1, bias + (size_t)(li + 1) * DIM, X0, nullptr, nullptr);
    const float* hin = (blk == 0) ? x : Hb;
    float* sout = (blk == NBLOCKS - 1) ? out : Sb;
    gemm2_kernel<false><<<ggrid, 256, 0, stream>>>(
        X0, WHI + w2, WLO + w2, bias + (size_t)(li + 2) * DIM, nullptr, hin, sout);
    if (blk < NBLOCKS - 1) {
      ln_kernel<<<BATCH, 256, 0, stream>>>(Sb, lnw + (size_t)blk * DIM,
                                           lnb + (size_t)blk * DIM, Hb, X0);
    }
  }
}

// Round 7
// 842.413 us; speedup vs baseline: 1.0173x; 1.0173x over previous
//
#include <hip/hip_runtime.h>
#include <cstdint>
#include <cstddef>

// ---------- problem constants ----------
#define DIM      1024
#define GROUP    16
#define LORA     20
#define NLAYERS  18
#define NBLOCKS  6
#define BATCH    8192
#define EPS      1e-5f

typedef __bf16 bf16_8 __attribute__((ext_vector_type(8)));
typedef __bf16 bf16_4 __attribute__((ext_vector_type(4)));
typedef float  f32x4  __attribute__((ext_vector_type(4)));

// ---------------------------------------------------------------------------
// Weight prep: W_total[l][o][k] = qw*scale + sum_r B[o][r]*A[r][k], split bf16
// hi/lo.  Outer-product form: thread owns 4 rows x 16 cols (64 f32 acc);
// per j: 4 ds_read_b128 of A (same addrs in both wave halves -> broadcast)
// + 4 B reads + 64 FMA.  LDS traffic 16x lower than row-serial form (R5/R6
// were LDS-issue-bound at 28% HBM).
// ---------------------------------------------------------------------------
__global__ __launch_bounds__(256) void wprep_kernel(
    const int* __restrict__ qw, const float* __restrict__ sc,
    const float* __restrict__ la, const float* __restrict__ lb,
    __bf16* __restrict__ whi, __bf16* __restrict__ wlo) {
  const int l  = blockIdx.x >> 6;          // 18 layers
  const int og = (blockIdx.x >> 1) & 31;   // 32 row-groups of 32
  const int cg = blockIdx.x & 1;           // 2 col-halves of 512
  const int tid = threadIdx.x;

  __shared__ float As[LORA * 512];   // 40 KB
  __shared__ float Bs[32 * LORA];    // 2.5 KB

  const float* Abase = la + (size_t)l * LORA * DIM + cg * 512;
#pragma unroll
  for (int i = 0; i < 10; ++i) {
    const int f4 = i * 256 + tid;
    const int j  = f4 >> 7;
    const int c4 = f4 & 127;
    ((float4*)As)[f4] = *(const float4*)(Abase + (size_t)j * DIM + c4 * 4);
  }
  const float* Bbase = lb + ((size_t)l * DIM + og * 32) * LORA;  // 640 floats
#pragma unroll
  for (int i = 0; i < 3; ++i) {
    const int idx = i * 256 + tid;
    if (idx < 32 * LORA) Bs[idx] = Bbase[idx];
  }
  __syncthreads();

  const int tc = tid & 31;                 // 32 col-groups of 16
  const int tr = tid >> 5;                 // 8 row-groups of 4
  const int c0 = tc * 16;
  const int r0 = tr * 4;

  float acc[4][16];
  size_t wb[4];
#pragma unroll
  for (int u = 0; u < 4; ++u) {
    const int orow = og * 32 + r0 + u;
    wb[u] = ((size_t)l * DIM + orow) * DIM + cg * 512 + c0;
    const float sv = sc[((size_t)l * DIM + orow) * (DIM / GROUP) + ((cg * 512 + c0) >> 4)];
    const int4* qp = (const int4*)&qw[wb[u]];
#pragma unroll
    for (int v = 0; v < 4; ++v) {
      const int4 q4 = qp[v];
      acc[u][v * 4 + 0] = q4.x * sv;
      acc[u][v * 4 + 1] = q4.y * sv;
      acc[u][v * 4 + 2] = q4.z * sv;
      acc[u][v * 4 + 3] = q4.w * sv;
    }
  }

#pragma unroll
  for (int j = 0; j < LORA; ++j) {
    const float4* Ap = (const float4*)&As[j * 512 + c0];
    const float4 a0 = Ap[0], a1 = Ap[1], a2 = Ap[2], a3 = Ap[3];
#pragma unroll
    for (int u = 0; u < 4; ++u) {
      const float bj = Bs[(r0 + u) * LORA + j];
      acc[u][0]  += bj * a0.x; acc[u][1]  += bj * a0.y;
      acc[u][2]  += bj * a0.z; acc[u][3]  += bj * a0.w;
      acc[u][4]  += bj * a1.x; acc[u][5]  += bj * a1.y;
      acc[u][6]  += bj * a1.z; acc[u][7]  += bj * a1.w;
      acc[u][8]  += bj * a2.x; acc[u][9]  += bj * a2.y;
      acc[u][10] += bj * a2.z; acc[u][11] += bj * a2.w;
      acc[u][12] += bj * a3.x; acc[u][13] += bj * a3.y;
      acc[u][14] += bj * a3.z; acc[u][15] += bj * a3.w;
    }
  }

#pragma unroll
  for (int u = 0; u < 4; ++u) {
#pragma unroll
    for (int h = 0; h < 2; ++h) {
      bf16_8 hv, lv;
#pragma unroll
      for (int e = 0; e < 8; ++e) {
        const float a = acc[u][h * 8 + e];
        const __bf16 hi = (__bf16)a;
        hv[e] = hi;
        lv[e] = (__bf16)(a - (float)hi);
      }
      *(bf16_8*)&whi[wb[u] + h * 8] = hv;
      *(bf16_8*)&wlo[wb[u] + h * 8] = lv;
    }
  }
}

// ---------------------------------------------------------------------------
// x prep: f32 -> single bf16
// ---------------------------------------------------------------------------
__global__ __launch_bounds__(256) void xprep_kernel(
    const float* __restrict__ x, __bf16* __restrict__ hi) {
  const size_t i = (size_t)blockIdx.x * 256 + threadIdx.x;
  const float4 v = ((const float4*)x)[i];
  const bf16_4 hv = {(__bf16)v.x, (__bf16)v.y, (__bf16)v.z, (__bf16)v.w};
  ((bf16_4*)hi)[i] = hv;
}

// ---------------------------------------------------------------------------
// 2-pass split-W bf16 GEMM (x single bf16; W = Wh + Wl).
// Tile 128x128, BK=32, 256 thr (4 waves 2x2), 3 LDS buffers (72 KB) with
// depth-2 prefetch + counted vmcnt(6): tile kt+1's loads get a full k-step
// (~700+ cyc) to cover HBM latency; kt+2's 6 loads stay in flight across the
// barrier (T4).  2 blocks/CU co-residency preserved (m97/m114 TLP regime).
// Block map: R5 chunk swizzle (tm-partitioned per XCD — R6's tn-per-XCD
// regressed: X re-streamed through every XCD's L2).
// ---------------------------------------------------------------------------
#define GBUF    12288   // elems per buffer (24 KB)
#define GOFF_WH 4096
#define GOFF_WL 8192

__device__ __forceinline__ void stageR(const __bf16* __restrict__ g, int row0, int k0,
                                       __bf16* lds, int tid) {
  const int wvbase = (tid >> 6) * 512;     // elems: wave-uniform LDS base
#pragma unroll
  for (int i = 0; i < 2; ++i) {
    const int D = i * 4096 + tid * 16;     // byte in 8KB region
    const int r  = D >> 6;                 // 64 B per row (BK=32 bf16)
    const int ce = (D & 63) >> 1;
    const __bf16* gp = g + (size_t)(row0 + r) * DIM + k0 + ce;
    __builtin_amdgcn_global_load_lds(
        (const __attribute__((address_space(1))) void*)gp,
        (__attribute__((address_space(3))) void*)(lds + i * 2048 + wvbase), 16, 0, 0);
  }
}

template <bool RELU_OUT>
__global__ __launch_bounds__(256, 2) void gemm2_kernel(
    const __bf16* __restrict__ X, const __bf16* __restrict__ Wh,
    const __bf16* __restrict__ Wl, const float* __restrict__ bias,
    __bf16* __restrict__ Oh,
    const float* __restrict__ Hin, float* __restrict__ Sout) {
  __shared__ __bf16 smem[3 * GBUF];        // 72 KB

  const int tid  = threadIdx.x;
  const int lane = tid & 63;
  const int wv   = tid >> 6;
  const int wm   = wv >> 1;                // feature half (2 x 64)
  const int wn   = wv & 1;                 // batch half   (2 x 64)
  // chunk swizzle: XCD gets 64 consecutive s = 8 tm x all tn (R5, measured best)
  const int s  = ((blockIdx.x & 7) << 6) + (blockIdx.x >> 3);
  const int tm = s >> 3, tn = s & 7;
  const int rowX = tm * 128, rowW = tn * 128;

  const int lr   = lane & 15;
  const int slot = lane >> 4;

  int offX[4], offW[4];
#pragma unroll
  for (int n = 0; n < 4; ++n) offX[n] = (wn * 64 + n * 16 + lr) * 32 + slot * 8;
#pragma unroll
  for (int m = 0; m < 4; ++m) offW[m] = GOFF_WH + (wm * 64 + m * 16 + lr) * 32 + slot * 8;

  f32x4 acc[4][4];
#pragma unroll
  for (int m = 0; m < 4; ++m)
#pragma unroll
    for (int n = 0; n < 4; ++n) acc[m][n] = f32x4{0.f, 0.f, 0.f, 0.f};

  auto stage_tile = [&](int k0, __bf16* sb) {
    stageR(X,  rowX, k0, sb, tid);
    stageR(Wh, rowW, k0, sb + GOFF_WH, tid);
    stageR(Wl, rowW, k0, sb + GOFF_WL, tid);
  };

  auto compute_tile = [&](const __bf16* buf) {
    bf16_8 xf[4];
#pragma unroll
    for (int n = 0; n < 4; ++n) xf[n] = *(const bf16_8*)&buf[offX[n]];
#pragma unroll
    for (int m = 0; m < 4; ++m) {
      const bf16_8 w_h = *(const bf16_8*)&buf[offW[m]];
      const bf16_8 w_l = *(const bf16_8*)&buf[offW[m] + (GOFF_WL - GOFF_WH)];
#pragma unroll
      for (int n = 0; n < 4; ++n) {
        acc[m][n] = __builtin_amdgcn_mfma_f32_16x16x32_bf16(w_h, xf[n], acc[m][n], 0, 0, 0);
        acc[m][n] = __builtin_amdgcn_mfma_f32_16x16x32_bf16(w_l, xf[n], acc[m][n], 0, 0, 0);
      }
    }
  };

  // prologue: tiles 0,1 in flight; wait tile 0 (6 newest = tile 1 stay out)
  stage_tile(0, smem);
  stage_tile(32, smem + GBUF);
  asm volatile("s_waitcnt vmcnt(6)" ::: "memory");
  __builtin_amdgcn_s_barrier();

  int cur = 0;
#pragma unroll 1
  for (int kt = 0; kt < 30; ++kt) {
    int pb = cur + 2; if (pb >= 3) pb -= 3;
    stage_tile((kt + 2) * 32, smem + pb * GBUF);   // into tile kt-1's buffer
    compute_tile(smem + cur * GBUF);
    // drain tile kt+1's 6 loads (oldest); kt+2's 6 newest stay in flight
    asm volatile("s_waitcnt vmcnt(6)" ::: "memory");
    __builtin_amdgcn_s_barrier();
    ++cur; if (cur == 3) cur = 0;
  }
  // tail: kt=30 ready; then drain all for kt=31
  compute_tile(smem + cur * GBUF);
  asm volatile("s_waitcnt vmcnt(0)" ::: "memory");
  __builtin_amdgcn_s_barrier();
  ++cur; if (cur == 3) cur = 0;
  compute_tile(smem + cur * GBUF);

  // epilogue: D reg-quad = 4 consecutive features of one batch row
  const int g4 = slot * 4;
#pragma unroll
  for (int m = 0; m < 4; ++m) {
    const int feat = tn * 128 + wm * 64 + m * 16 + g4;
    const float4 bv = *(const float4*)&bias[feat];
#pragma unroll
    for (int n = 0; n < 4; ++n) {
      const int nb = tm * 128 + wn * 64 + n * 16 + lr;
      const size_t base = (size_t)nb * DIM + feat;
      float v0 = acc[m][n][0] + bv.x;
      float v1 = acc[m][n][1] + bv.y;
      float v2 = acc[m][n][2] + bv.z;
      float v3 = acc[m][n][3] + bv.w;
      if constexpr (RELU_OUT) {
        const bf16_4 hv = {(__bf16)fmaxf(v0, 0.f), (__bf16)fmaxf(v1, 0.f),
                           (__bf16)fmaxf(v2, 0.f), (__bf16)fmaxf(v3, 0.f)};
        *(bf16_4*)&Oh[base] = hv;
      } else {
        const float4 h = *(const float4*)&Hin[base];
        *(float4*)&Sout[base] = float4{v0 + h.x, v1 + h.y, v2 + h.z, v3 + h.w};
      }
    }
  }
}

// ---------------------------------------------------------------------------
// Row LayerNorm: H = LN(S)*w+b (f32) plus bf16 cast (next block's GEMM input).
// ---------------------------------------------------------------------------
__global__ __launch_bounds__(256) void ln_kernel(
    const float* __restrict__ S, const float* __restrict__ w,
    const float* __restrict__ b, float* __restrict__ H,
    __bf16* __restrict__ phi) {
  const int row = blockIdx.x;
  const int tid = threadIdx.x;
  const int lane = tid & 63;
  const int wv = tid >> 6;
  const float4 v = ((const float4*)(S + (size_t)row * DIM))[tid];

  float s = v.x + v.y + v.z + v.w;
#pragma unroll
  for (int m = 32; m; m >>= 1) s += __shfl_xor(s, m, 64);
  __shared__ float red[8];
  if (lane == 0) red[wv] = s;
  __syncthreads();
  const float mean = (red[0] + red[1] + red[2] + red[3]) * (1.f / DIM);

  const float d0 = v.x - mean, d1 = v.y - mean, d2 = v.z - mean, d3 = v.w - mean;
  float q = d0 * d0 + d1 * d1 + d2 * d2 + d3 * d3;
#pragma unroll
  for (int m = 32; m; m >>= 1) q += __shfl_xor(q, m, 64);
  if (lane == 0) red[4 + wv] = q;
  __syncthreads();
  const float var = (red[4] + red[5] + red[6] + red[7]) * (1.f / DIM);
  const float inv = 1.f / sqrtf(var + EPS);

  const float4 wv4 = ((const float4*)w)[tid];
  const float4 bv4 = ((const float4*)b)[tid];
  const float y0 = d0 * inv * wv4.x + bv4.x;
  const float y1 = d1 * inv * wv4.y + bv4.y;
  const float y2 = d2 * inv * wv4.z + bv4.z;
  const float y3 = d3 * inv * wv4.w + bv4.w;

  ((float4*)(H + (size_t)row * DIM))[tid] = float4{y0, y1, y2, y3};
  const bf16_4 hv = {(__bf16)y0, (__bf16)y1, (__bf16)y2, (__bf16)y3};
  ((bf16_4*)phi)[(size_t)row * (DIM / 4) + tid] = hv;
}

// ---------------------------------------------------------------------------
// launch
// ---------------------------------------------------------------------------
extern "C" void kernel_launch(void* const* d_in, const int* in_sizes, int n_in,
                              void* d_out, int out_size, void* d_ws, size_t ws_size,
                              hipStream_t stream) {
  const float* x   = (const float*)d_in[0];
  const int*   qw  = (const int*)d_in[1];
  const float* sc  = (const float*)d_in[2];
  const float* bias= (const float*)d_in[3];
  const float* la  = (const float*)d_in[4];
  const float* lb  = (const float*)d_in[5];
  const float* lnw = (const float*)d_in[6];
  const float* lnb = (const float*)d_in[7];
  float* out = (float*)d_out;
  char* ws = (char*)d_ws;

  // workspace layout (bytes): WHI 36M | WLO 36M | X0 16M | X1 16M | Sb 32M | Hb 32M
  __bf16* WHI = (__bf16*)(ws);
  __bf16* WLO = (__bf16*)(ws + 37748736);
  __bf16* X0  = (__bf16*)(ws + 75497472);
  __bf16* X1  = (__bf16*)(ws + 92274688);
  float*  Sb  = (float*)(ws + 109051904);
  float*  Hb  = (float*)(ws + 142606336);
  (void)ws_size; (void)in_sizes; (void)n_in; (void)out_size;

  xprep_kernel<<<BATCH * DIM / (256 * 4), 256, 0, stream>>>(x, X0);
  wprep_kernel<<<NLAYERS * 64, 256, 0, stream>>>(qw, sc, la, lb, WHI, WLO);

  const dim3 ggrid(BATCH / 128 * (DIM / 128));  // 64 * 8 = 512
  for (int blk = 0; blk < NBLOCKS; ++blk) {
    const int li = blk * 3;
    const size_t w0 = (size_t)li * DIM * DIM;
    const size_t w1 = (size_t)(li + 1) * DIM * DIM;
    const size_t w2 = (size_t)(li + 2) * DIM * DIM;

    gemm2_kernel<true><<<ggrid, 256, 0, stream>>>(
        X0, WHI + w0, WLO + w0, bias + (size_t)li * DIM, X1, nullptr, nullptr);
    gemm2_kernel<true><<<ggrid, 256, 0, stream>>>(
        X1, WHI + w1, WLO + w1, bias + (size_t)(li + 1) * DIM, X0, nullptr, nullptr);
    const float* hin = (blk == 0) ? x : Hb;
    float* sout = (blk == NBLOCKS - 1) ? out : Sb;
    gemm2_kernel<false><<<ggrid, 256, 0, stream>>>(
        X0, WHI + w2, WLO + w2, bias + (size_t)(li + 2) * DIM, nullptr, hin, sout);
    if (blk < NBLOCKS - 1) {
      ln_kernel<<<BATCH, 256, 0, stream>>>(Sb, lnw + (size_t)blk * DIM,
                                           lnb + (size_t)blk * DIM, Hb, X0);
    }
  }
}

// Round 8
// 785.791 us; speedup vs baseline: 1.0907x; 1.0721x over previous
//
#include <hip/hip_runtime.h>
#include <cstdint>
#include <cstddef>

// ---------- problem constants ----------
#define DIM      1024
#define GROUP    16
#define LORA     20
#define NLAYERS  18
#define NBLOCKS  6
#define BATCH    8192
#define EPS      1e-5f

typedef __bf16 bf16_8 __attribute__((ext_vector_type(8)));
typedef __bf16 bf16_4 __attribute__((ext_vector_type(4)));
typedef float  f32x4  __attribute__((ext_vector_type(4)));

// ---------------------------------------------------------------------------
// Weight prep: W_total[l][o][k] = qw*scale + sum_r B[o][r]*A[r][k], split bf16
// hi/lo.  Thread owns 4 rows x 16 cols (64 f32 acc).  A is read DIRECTLY from
// global per j (lane-coalesced 2048B per 32-lane group; ~368MB L2 traffic
// total, ~10us aggregate) — R7's LDS-As had 64B lane stride = 2-bank access
// (4.4M conflicts, 82us).  Only Bs (2.5KB, broadcast reads) stays in LDS.
// ---------------------------------------------------------------------------
__global__ __launch_bounds__(256) void wprep_kernel(
    const int* __restrict__ qw, const float* __restrict__ sc,
    const float* __restrict__ la, const float* __restrict__ lb,
    __bf16* __restrict__ whi, __bf16* __restrict__ wlo) {
  const int l  = blockIdx.x >> 6;          // 18 layers
  const int og = (blockIdx.x >> 1) & 31;   // 32 row-groups of 32
  const int cg = blockIdx.x & 1;           // 2 col-halves of 512
  const int tid = threadIdx.x;

  __shared__ float Bs[32 * LORA];          // 2.5 KB

  const float* Bbase = lb + ((size_t)l * DIM + og * 32) * LORA;  // 640 floats
#pragma unroll
  for (int i = 0; i < 3; ++i) {
    const int idx = i * 256 + tid;
    if (idx < 32 * LORA) Bs[idx] = Bbase[idx];
  }
  __syncthreads();

  const int tc = tid & 31;                 // 32 col-groups of 16
  const int tr = tid >> 5;                 // 8 row-groups of 4
  const int c0 = tc * 16;
  const int r0 = tr * 4;

  float acc[4][16];
  size_t wb[4];
#pragma unroll
  for (int u = 0; u < 4; ++u) {
    const int orow = og * 32 + r0 + u;
    wb[u] = ((size_t)l * DIM + orow) * DIM + cg * 512 + c0;
    const float sv = sc[((size_t)l * DIM + orow) * (DIM / GROUP) + ((cg * 512 + c0) >> 4)];
    const int4* qp = (const int4*)&qw[wb[u]];
#pragma unroll
    for (int v = 0; v < 4; ++v) {
      const int4 q4 = qp[v];
      acc[u][v * 4 + 0] = q4.x * sv;
      acc[u][v * 4 + 1] = q4.y * sv;
      acc[u][v * 4 + 2] = q4.z * sv;
      acc[u][v * 4 + 3] = q4.w * sv;
    }
  }

  const float* Ab = la + (size_t)l * LORA * DIM + cg * 512 + c0;
#pragma unroll 2
  for (int j = 0; j < LORA; ++j) {
    const float4* Ap = (const float4*)(Ab + (size_t)j * DIM);
    const float4 a0 = Ap[0], a1 = Ap[1], a2 = Ap[2], a3 = Ap[3];
#pragma unroll
    for (int u = 0; u < 4; ++u) {
      const float bj = Bs[(r0 + u) * LORA + j];
      acc[u][0]  += bj * a0.x; acc[u][1]  += bj * a0.y;
      acc[u][2]  += bj * a0.z; acc[u][3]  += bj * a0.w;
      acc[u][4]  += bj * a1.x; acc[u][5]  += bj * a1.y;
      acc[u][6]  += bj * a1.z; acc[u][7]  += bj * a1.w;
      acc[u][8]  += bj * a2.x; acc[u][9]  += bj * a2.y;
      acc[u][10] += bj * a2.z; acc[u][11] += bj * a2.w;
      acc[u][12] += bj * a3.x; acc[u][13] += bj * a3.y;
      acc[u][14] += bj * a3.z; acc[u][15] += bj * a3.w;
    }
  }

#pragma unroll
  for (int u = 0; u < 4; ++u) {
#pragma unroll
    for (int h = 0; h < 2; ++h) {
      bf16_8 hv, lv;
#pragma unroll
      for (int e = 0; e < 8; ++e) {
        const float a = acc[u][h * 8 + e];
        const __bf16 hi = (__bf16)a;
        hv[e] = hi;
        lv[e] = (__bf16)(a - (float)hi);
      }
      *(bf16_8*)&whi[wb[u] + h * 8] = hv;
      *(bf16_8*)&wlo[wb[u] + h * 8] = lv;
    }
  }
}

// ---------------------------------------------------------------------------
// x prep: f32 -> single bf16
// ---------------------------------------------------------------------------
__global__ __launch_bounds__(256) void xprep_kernel(
    const float* __restrict__ x, __bf16* __restrict__ hi) {
  const size_t i = (size_t)blockIdx.x * 256 + threadIdx.x;
  const float4 v = ((const float4*)x)[i];
  const bf16_4 hv = {(__bf16)v.x, (__bf16)v.y, (__bf16)v.z, (__bf16)v.w};
  ((bf16_4*)hi)[i] = hv;
}

// ---------------------------------------------------------------------------
// 2-pass split-W bf16 GEMM (x single bf16; W = Wh + Wl).
// Tile 256 batch x 128 feat, BK=32, 512 thr (8 waves: 4 batch x 2 feat),
// per-wave 64x64 output.  Grid = 32x8 = 256 = exactly 1 block/CU (8 waves =
// 2/SIMD, same wave count as R7's 2x4 but HALF the W staging traffic:
// W staged = (8192/BM)*4MB = 128MB vs R7's 256MB — staging flow was ~10TB/s
// aggregate, the binding constraint).  3 x 32KB buffers, counted vmcnt(4).
// ---------------------------------------------------------------------------
#define GBUF    16384   // elems per buffer (32 KB)
#define GOFF_WH 8192    // X 256x32 elems first
#define GOFF_WL 12288

template <int NISSUE>
__device__ __forceinline__ void stageR(const __bf16* __restrict__ g, int row0, int k0,
                                       __bf16* lds, int tid) {
  const int wvbase = (tid >> 6) * 1024;    // bytes... no: elems? see below
#pragma unroll
  for (int i = 0; i < NISSUE; ++i) {
    const int D = i * 8192 + tid * 16;     // linear byte in region (512 thr x 16B = 8KB/issue)
    const int r  = D >> 6;                 // 64 B per row (BK=32 bf16)
    const int ce = (D & 63) >> 1;
    const __bf16* gp = g + (size_t)(row0 + r) * DIM + k0 + ce;
    __builtin_amdgcn_global_load_lds(
        (const __attribute__((address_space(1))) void*)gp,
        (__attribute__((address_space(3))) void*)(lds + i * 4096 + (tid >> 6) * 512), 16, 0, 0);
  }
  (void)wvbase;
}

template <bool RELU_OUT>
__global__ __launch_bounds__(512, 1) void gemm2_kernel(
    const __bf16* __restrict__ X, const __bf16* __restrict__ Wh,
    const __bf16* __restrict__ Wl, const float* __restrict__ bias,
    __bf16* __restrict__ Oh,
    const float* __restrict__ Hin, float* __restrict__ Sout) {
  __shared__ __bf16 smem[3 * GBUF];        // 96 KB

  const int tid  = threadIdx.x;
  const int lane = tid & 63;
  const int wv   = tid >> 6;
  const int wm   = wv >> 2;                // feature half (2 x 64)
  const int wn2  = wv & 3;                 // batch quarter (4 x 64)
  // XCD chunk: xcd gets tm in [4x..4x+3] x all 8 tn (X panels L2-local)
  const int xcd = blockIdx.x & 7;
  const int kk  = blockIdx.x >> 3;         // 0..31
  const int tm  = xcd * 4 + (kk >> 3);     // 0..31
  const int tn  = kk & 7;                  // 0..7
  const int rowX = tm * 256, rowW = tn * 128;

  const int lr   = lane & 15;
  const int slot = lane >> 4;

  int offX[4], offW[4];
#pragma unroll
  for (int n = 0; n < 4; ++n) offX[n] = (wn2 * 64 + n * 16 + lr) * 32 + slot * 8;
#pragma unroll
  for (int m = 0; m < 4; ++m) offW[m] = GOFF_WH + (wm * 64 + m * 16 + lr) * 32 + slot * 8;

  f32x4 acc[4][4];
#pragma unroll
  for (int m = 0; m < 4; ++m)
#pragma unroll
    for (int n = 0; n < 4; ++n) acc[m][n] = f32x4{0.f, 0.f, 0.f, 0.f};

  auto stage_tile = [&](int k0, __bf16* sb) {
    stageR<2>(X,  rowX, k0, sb, tid);
    stageR<1>(Wh, rowW, k0, sb + GOFF_WH, tid);
    stageR<1>(Wl, rowW, k0, sb + GOFF_WL, tid);
  };

  auto compute_tile = [&](const __bf16* buf) {
    bf16_8 xf[4];
#pragma unroll
    for (int n = 0; n < 4; ++n) xf[n] = *(const bf16_8*)&buf[offX[n]];
#pragma unroll
    for (int m = 0; m < 4; ++m) {
      const bf16_8 w_h = *(const bf16_8*)&buf[offW[m]];
      const bf16_8 w_l = *(const bf16_8*)&buf[offW[m] + (GOFF_WL - GOFF_WH)];
#pragma unroll
      for (int n = 0; n < 4; ++n) {
        acc[m][n] = __builtin_amdgcn_mfma_f32_16x16x32_bf16(w_h, xf[n], acc[m][n], 0, 0, 0);
        acc[m][n] = __builtin_amdgcn_mfma_f32_16x16x32_bf16(w_l, xf[n], acc[m][n], 0, 0, 0);
      }
    }
  };

  // prologue: tiles 0,1 in flight; wait tile 0 (4 newest = tile 1 stay out)
  stage_tile(0, smem);
  stage_tile(32, smem + GBUF);
  asm volatile("s_waitcnt vmcnt(4)" ::: "memory");
  __builtin_amdgcn_s_barrier();

  int cur = 0;
#pragma unroll 1
  for (int kt = 0; kt < 30; ++kt) {
    int pb = cur + 2; if (pb >= 3) pb -= 3;
    stage_tile((kt + 2) * 32, smem + pb * GBUF);
    compute_tile(smem + cur * GBUF);
    // drain tile kt+1's 4 loads (oldest); kt+2's 4 newest stay in flight
    asm volatile("s_waitcnt vmcnt(4)" ::: "memory");
    __builtin_amdgcn_s_barrier();
    ++cur; if (cur == 3) cur = 0;
  }
  compute_tile(smem + cur * GBUF);
  asm volatile("s_waitcnt vmcnt(0)" ::: "memory");
  __builtin_amdgcn_s_barrier();
  ++cur; if (cur == 3) cur = 0;
  compute_tile(smem + cur * GBUF);

  // epilogue: D reg-quad = 4 consecutive features of one batch row
  const int g4 = slot * 4;
#pragma unroll
  for (int m = 0; m < 4; ++m) {
    const int feat = tn * 128 + wm * 64 + m * 16 + g4;
    const float4 bv = *(const float4*)&bias[feat];
#pragma unroll
    for (int n = 0; n < 4; ++n) {
      const int nb = tm * 256 + wn2 * 64 + n * 16 + lr;
      const size_t base = (size_t)nb * DIM + feat;
      float v0 = acc[m][n][0] + bv.x;
      float v1 = acc[m][n][1] + bv.y;
      float v2 = acc[m][n][2] + bv.z;
      float v3 = acc[m][n][3] + bv.w;
      if constexpr (RELU_OUT) {
        const bf16_4 hv = {(__bf16)fmaxf(v0, 0.f), (__bf16)fmaxf(v1, 0.f),
                           (__bf16)fmaxf(v2, 0.f), (__bf16)fmaxf(v3, 0.f)};
        *(bf16_4*)&Oh[base] = hv;
      } else {
        const float4 h = *(const float4*)&Hin[base];
        *(float4*)&Sout[base] = float4{v0 + h.x, v1 + h.y, v2 + h.z, v3 + h.w};
      }
    }
  }
}

// ---------------------------------------------------------------------------
// Row LayerNorm: H = LN(S)*w+b (f32) plus bf16 cast (next block's GEMM input).
// ---------------------------------------------------------------------------
__global__ __launch_bounds__(256) void ln_kernel(
    const float* __restrict__ S, const float* __restrict__ w,
    const float* __restrict__ b, float* __restrict__ H,
    __bf16* __restrict__ phi) {
  const int row = blockIdx.x;
  const int tid = threadIdx.x;
  const int lane = tid & 63;
  const int wv = tid >> 6;
  const float4 v = ((const float4*)(S + (size_t)row * DIM))[tid];

  float s = v.x + v.y + v.z + v.w;
#pragma unroll
  for (int m = 32; m; m >>= 1) s += __shfl_xor(s, m, 64);
  __shared__ float red[8];
  if (lane == 0) red[wv] = s;
  __syncthreads();
  const float mean = (red[0] + red[1] + red[2] + red[3]) * (1.f / DIM);

  const float d0 = v.x - mean, d1 = v.y - mean, d2 = v.z - mean, d3 = v.w - mean;
  float q = d0 * d0 + d1 * d1 + d2 * d2 + d3 * d3;
#pragma unroll
  for (int m = 32; m; m >>= 1) q += __shfl_xor(q, m, 64);
  if (lane == 0) red[4 + wv] = q;
  __syncthreads();
  const float var = (red[4] + red[5] + red[6] + red[7]) * (1.f / DIM);
  const float inv = 1.f / sqrtf(var + EPS);

  const float4 wv4 = ((const float4*)w)[tid];
  const float4 bv4 = ((const float4*)b)[tid];
  const float y0 = d0 * inv * wv4.x + bv4.x;
  const float y1 = d1 * inv * wv4.y + bv4.y;
  const float y2 = d2 * inv * wv4.z + bv4.z;
  const float y3 = d3 * inv * wv4.w + bv4.w;

  ((float4*)(H + (size_t)row * DIM))[tid] = float4{y0, y1, y2, y3};
  const bf16_4 hv = {(__bf16)y0, (__bf16)y1, (__bf16)y2, (__bf16)y3};
  ((bf16_4*)phi)[(size_t)row * (DIM / 4) + tid] = hv;
}

// ---------------------------------------------------------------------------
// launch
// ---------------------------------------------------------------------------
extern "C" void kernel_launch(void* const* d_in, const int* in_sizes, int n_in,
                              void* d_out, int out_size, void* d_ws, size_t ws_size,
                              hipStream_t stream) {
  const float* x   = (const float*)d_in[0];
  const int*   qw  = (const int*)d_in[1];
  const float* sc  = (const float*)d_in[2];
  const float* bias= (const float*)d_in[3];
  const float* la  = (const float*)d_in[4];
  const float* lb  = (const float*)d_in[5];
  const float* lnw = (const float*)d_in[6];
  const float* lnb = (const float*)d_in[7];
  float* out = (float*)d_out;
  char* ws = (char*)d_ws;

  // workspace layout (bytes): WHI 36M | WLO 36M | X0 16M | X1 16M | Sb 32M | Hb 32M
  __bf16* WHI = (__bf16*)(ws);
  __bf16* WLO = (__bf16*)(ws + 37748736);
  __bf16* X0  = (__bf16*)(ws + 75497472);
  __bf16* X1  = (__bf16*)(ws + 92274688);
  float*  Sb  = (float*)(ws + 109051904);
  float*  Hb  = (float*)(ws + 142606336);
  (void)ws_size; (void)in_sizes; (void)n_in; (void)out_size;

  xprep_kernel<<<BATCH * DIM / (256 * 4), 256, 0, stream>>>(x, X0);
  wprep_kernel<<<NLAYERS * 64, 256, 0, stream>>>(qw, sc, la, lb, WHI, WLO);

  const dim3 ggrid(BATCH / 256 * (DIM / 128));  // 32 * 8 = 256 = 1 block/CU
  for (int blk = 0; blk < NBLOCKS; ++blk) {
    const int li = blk * 3;
    const size_t w0 = (size_t)li * DIM * DIM;
    const size_t w1 = (size_t)(li + 1) * DIM * DIM;
    const size_t w2 = (size_t)(li + 2) * DIM * DIM;

    gemm2_kernel<true><<<ggrid, 512, 0, stream>>>(
        X0, WHI + w0, WLO + w0, bias + (size_t)li * DIM, X1, nullptr, nullptr);
    gemm2_kernel<true><<<ggrid, 512, 0, stream>>>(
        X1, WHI + w1, WLO + w1, bias + (size_t)(li + 1) * DIM, X0, nullptr, nullptr);
    const float* hin = (blk == 0) ? x : Hb;
    float* sout = (blk == NBLOCKS - 1) ? out : Sb;
    gemm2_kernel<false><<<ggrid, 512, 0, stream>>>(
        X0, WHI + w2, WLO + w2, bias + (size_t)(li + 2) * DIM, nullptr, hin, sout);
    if (blk < NBLOCKS - 1) {
      ln_kernel<<<BATCH, 256, 0, stream>>>(Sb, lnw + (size_t)blk * DIM,
                                           lnb + (size_t)blk * DIM, Hb, X0);
    }
  }
}